// Round 6
// baseline (112.039 us; speedup 1.0000x reference)
//
#include <hip/hip_runtime.h>
#include <hip/hip_bf16.h>

#define NCOUNT 8
#define B_TOTAL 131072
#define W_WIN 1024
#define BLK 256
#define AT_STRIDE 1048   // bf16 elems per At row: 1024 + 24 pad

typedef __attribute__((ext_vector_type(8))) short bf16x8;
typedef __attribute__((ext_vector_type(4))) float f32x4;
typedef __attribute__((ext_vector_type(16))) float f32x16;

__device__ inline short bf_cvt(float x) {
    __hip_bfloat16 h = __float2bfloat16(x);   // RNE
    return *reinterpret_cast<short*>(&h);
}
__device__ inline bf16x8 cvt8(float4 a, float4 b) {
    bf16x8 r;
    r[0] = bf_cvt(a.x); r[1] = bf_cvt(a.y); r[2] = bf_cvt(a.z); r[3] = bf_cvt(a.w);
    r[4] = bf_cvt(b.x); r[5] = bf_cvt(b.y); r[6] = bf_cvt(b.z); r[7] = bf_cvt(b.w);
    return r;
}

__global__ __launch_bounds__(BLK, 2) void nnue_mfma_kernel(
    const float* __restrict__ accum,
    const float* __restrict__ us,
    const float* __restrict__ l1_w,
    const float* __restrict__ l1_b,
    const float* __restrict__ l2_w,
    const float* __restrict__ l2_b,
    const float* __restrict__ out_w,
    const float* __restrict__ out_b,
    const int*   __restrict__ psqt_indices,
    const int*   __restrict__ lsi,
    float*       __restrict__ out)
{
    __shared__ int list[W_WIN];
    __shared__ int cnt;
    __shared__ __align__(16) short At[16][AT_STRIDE];   // bf16 tile (single buffer)
    __shared__ __align__(16) float psq[2][16][16];      // psqt floats, parity = tile&1
    __shared__ __align__(16) float l1part[4][64][4];    // split-K partials
    __shared__ __align__(16) float l1y[16 * 20];        // wave-0 activation exchange
    __shared__ float epiw[64];                          // [0:32) l2_b row, [32:64) out_w row

    const int l    = blockIdx.y;
    const int base = blockIdx.x * W_WIN;
    const int tid  = threadIdx.x;
    const int lane = tid & 63;
    const int wid  = tid >> 6;

    if (tid == 0) cnt = 0;
    __syncthreads();
    for (int i = tid; i < W_WIN; i += BLK)
        if (lsi[base + i] == l) list[atomicAdd(&cnt, 1)] = base + i;
    if (tid < 64)
        epiw[tid] = (tid < 32) ? l2_b[l * 32 + tid] : out_w[l * 32 + (tid - 32)];
    __syncthreads();
    const int n = cnt;
    if (n == 0) return;

    const int jlow  = lane & 15;
    const int g     = lane >> 4;
    const int col32 = lane & 31;
    const int h     = lane >> 5;

    // ---- persistent weights in registers ----
    const float* wrow = l1_w + (((size_t)l * 16 + jlow) << 10);
    bf16x8 wfrag[8];
    #pragma unroll
    for (int i = 0; i < 8; ++i) {
        const int kf = (wid * 8 + i) * 32 + g * 8;
        wfrag[i] = cvt8(*(const float4*)(wrow + kf), *(const float4*)(wrow + kf + 4));
    }
    const float* w2row = l2_w + ((size_t)l * 32 + col32) * 16 + h * 8;
    const bf16x8 w2frag = cvt8(*(const float4*)(w2row), *(const float4*)(w2row + 4));
    const float l1bias = l1_b[l * 16 + jlow];
    const float outb   = out_b[l];

    const int srow  = tid >> 5;   // rows srow, srow+8
    const int scol8 = tid & 31;   // 8-float chunk lane
    const int pr    = tid >> 2;   // psq staging row (tid<64)
    const int ppart = tid & 3;
    const int psf   = (ppart < 2) ? (512 + 4 * ppart) : (1032 + 4 * (ppart - 2));

    // ---- depth-2 register prefetch sets ----
    float4 pfa0[8], pfb0[8], pfq0; float usn0 = 0.f; int pin0 = 0;
    float4 pfa1[8], pfb1[8], pfq1; float usn1 = 0.f; int pin1 = 0;

    auto issue_pf = [&](int tbn, float4 (&pa)[8], float4 (&pb)[8], float4& pq,
                        float& usn, int& pin) {
        #pragma unroll
        for (int rr = 0; rr < 2; ++rr) {
            const int mi = tbn + rr * 8 + srow;
            const float* src = accum + (size_t)list[mi < n ? mi : n - 1] * 1040;
            #pragma unroll
            for (int p = 0; p < 4; ++p) {
                const int sf = 8 * (scol8 + 32 * p) + (p >= 2 ? 8 : 0);
                pa[rr * 4 + p] = *(const float4*)(src + sf);
                pb[rr * 4 + p] = *(const float4*)(src + sf + 4);
            }
        }
        if (tid < 64) {
            const int mi = tbn + pr;
            const float* src = accum + (size_t)list[mi < n ? mi : n - 1] * 1040;
            pq = *(const float4*)(src + psf);
        }
        if (wid == 0 && lane < 16) {
            const int mi = tbn + jlow;
            const int s  = list[mi < n ? mi : n - 1];
            usn = us[s];
            pin = psqt_indices[s];
        }
    };

    auto stage = [&](const float4 (&pa)[8], const float4 (&pb)[8], const float4& pq,
                     int qbuf) {
        #pragma unroll
        for (int rr = 0; rr < 2; ++rr) {
            const int row = rr * 8 + srow;
            #pragma unroll
            for (int p = 0; p < 4; ++p)
                *(bf16x8*)&At[row][8 * (scol8 + 32 * p)] = cvt8(pa[rr * 4 + p], pb[rr * 4 + p]);
        }
        if (tid < 64) *(float4*)&psq[qbuf][pr][ppart * 4] = pq;
    };

    auto compute = [&]() {
        f32x4 acc = {0.f, 0.f, 0.f, 0.f};
        #pragma unroll
        for (int i = 0; i < 8; ++i) {
            const int kf = (wid * 8 + i) * 32 + g * 8;
            bf16x8 afrag = *(const bf16x8*)&At[jlow][kf];
            acc = __builtin_amdgcn_mfma_f32_16x16x32_bf16(afrag, wfrag[i], acc, 0, 0, 0);
        }
        *(f32x4*)&l1part[wid][lane][0] = acc;
    };

    auto epilogue = [&](int tb_, int qbuf, float us_e, int pi_e) {
        if (wid != 0) return;
        f32x4 t0 = *(const f32x4*)&l1part[0][lane][0];
        f32x4 t1 = *(const f32x4*)&l1part[1][lane][0];
        f32x4 t2 = *(const f32x4*)&l1part[2][lane][0];
        f32x4 t3 = *(const f32x4*)&l1part[3][lane][0];
        #pragma unroll
        for (int r = 0; r < 4; ++r) {
            float v = fminf(fmaxf(t0[r] + t1[r] + t2[r] + t3[r] + l1bias, 0.f), 1.f);
            l1y[(g * 4 + r) * 20 + jlow] = v;
        }
        __builtin_amdgcn_wave_barrier();
        asm volatile("s_waitcnt lgkmcnt(0)" ::: "memory");

        const float* lyr = l1y + (col32 & 15) * 20 + h * 8;
        float4 y0 = *(const float4*)(lyr);
        float4 y1 = *(const float4*)(lyr + 4);
        const bf16x8 b2frag = cvt8(y0, y1);

        f32x16 acc2 = {};
        acc2 = __builtin_amdgcn_mfma_f32_32x32x16_bf16(w2frag, b2frag, acc2, 0, 0, 0);

        float partial = 0.f;
        #pragma unroll
        for (int r = 0; r < 16; ++r) {
            const int j2 = (r & 3) + 8 * (r >> 2) + 4 * h;
            float v = fminf(fmaxf(acc2[r] + epiw[j2], 0.f), 1.f);
            partial += v * epiw[32 + j2];
        }
        partial += __shfl_xor(partial, 32);

        if (lane < 16 && tb_ + jlow < n) {
            const int s = list[tb_ + jlow];
            const float wp = psq[qbuf][jlow][pi_e];
            const float bp = psq[qbuf][jlow][8 + pi_e];
            out[s] = partial + outb + (wp - bp) * (us_e - 0.5f);
        }
    };

    // ---- prologue: fill both prefetch sets ----
    issue_pf(0, pfa0, pfb0, pfq0, usn0, pin0);
    if (n > 16) issue_pf(16, pfa1, pfb1, pfq1, usn1, pin1);

    for (int tb = 0; tb < n; tb += 32) {
        // ================= tile A (even) =================
        stage(pfa0, pfb0, pfq0, 0);
        __syncthreads();                        // At, psq[0] ready
        float us_e = usn0; int pi_e = pin0;
        if (tb + 32 < n) issue_pf(tb + 32, pfa0, pfb0, pfq0, usn0, pin0);
        compute();
        __syncthreads();                        // l1part ready; At consumed
        epilogue(tb, 0, us_e, pi_e);            // wave0; others fall through

        // ================= tile B (odd) ==================
        if (tb + 16 < n) {
            stage(pfa1, pfb1, pfq1, 1);
            __syncthreads();                    // At, psq[1] ready
            us_e = usn1; pi_e = pin1;
            if (tb + 48 < n) issue_pf(tb + 48, pfa1, pfb1, pfq1, usn1, pin1);
            compute();
            __syncthreads();                    // l1part ready; At consumed
            epilogue(tb + 16, 1, us_e, pi_e);
        }
    }
}

extern "C" void kernel_launch(void* const* d_in, const int* in_sizes, int n_in,
                              void* d_out, int out_size, void* d_ws, size_t ws_size,
                              hipStream_t stream) {
    const float* accum = (const float*)d_in[0];
    const float* us    = (const float*)d_in[1];
    const float* l1_w  = (const float*)d_in[2];
    const float* l1_b  = (const float*)d_in[3];
    const float* l2_w  = (const float*)d_in[4];
    const float* l2_b  = (const float*)d_in[5];
    const float* out_w = (const float*)d_in[6];
    const float* out_b = (const float*)d_in[7];
    const int*   psqt  = (const int*)d_in[8];
    const int*   lsi   = (const int*)d_in[9];
    float* out = (float*)d_out;

    dim3 grid(B_TOTAL / W_WIN, NCOUNT);
    nnue_mfma_kernel<<<grid, BLK, 0, stream>>>(
        accum, us, l1_w, l1_b, l2_w, l2_b, out_w, out_b, psqt, lsi, out);
}

// Round 7
// 109.242 us; speedup vs baseline: 1.0256x; 1.0256x over previous
//
#include <hip/hip_runtime.h>
#include <hip/hip_bf16.h>

#define NCOUNT 8
#define B_TOTAL 131072
#define W_WIN 1024
#define BLK 256

typedef __attribute__((ext_vector_type(8))) short bf16x8;
typedef __attribute__((ext_vector_type(4))) float f32x4;
typedef __attribute__((ext_vector_type(16))) float f32x16;

__device__ inline short bf_cvt(float x) {
    __hip_bfloat16 h = __float2bfloat16(x);   // RNE
    return *reinterpret_cast<short*>(&h);
}
__device__ inline bf16x8 cvt8(float4 a, float4 b) {
    bf16x8 r;
    r[0] = bf_cvt(a.x); r[1] = bf_cvt(a.y); r[2] = bf_cvt(a.z); r[3] = bf_cvt(a.w);
    r[4] = bf_cvt(b.x); r[5] = bf_cvt(b.y); r[6] = bf_cvt(b.z); r[7] = bf_cvt(b.w);
    return r;
}

// XOR-swizzled element index into At (bf16 elems, row stride 1024).
// byte ^= ((row&7)<<4)  <=>  elem ^= ((row&7)<<3). Same involution on write+read.
__device__ inline int atx(int row, int kbf) {
    return (row * 1024 + kbf) ^ ((row & 7) << 3);
}

__global__ __launch_bounds__(BLK, 2) void nnue_mfma_kernel(
    const float* __restrict__ accum,
    const float* __restrict__ us,
    const float* __restrict__ l1_w,
    const float* __restrict__ l1_b,
    const float* __restrict__ l2_w,
    const float* __restrict__ l2_b,
    const float* __restrict__ out_w,
    const float* __restrict__ out_b,
    const int*   __restrict__ psqt_indices,
    const int*   __restrict__ lsi,
    float*       __restrict__ out)
{
    __shared__ unsigned short list[W_WIN];              // window-local offsets
    __shared__ int cnt;
    __shared__ __align__(16) short At[32 * 1024];       // 64 KB bf16 tile, swizzled
    __shared__ __align__(16) float psq[2][32][16];      // psqt floats, parity buf
    __shared__ __align__(16) f32x4 l1part[2][3][64];    // split-K partials (3 other waves)
    __shared__ __align__(16) float l1y[2][16 * 20];     // per-group activation exchange
    __shared__ float epiw[64];                          // [0:32) l2_b, [32:64) out_w

    const int l    = blockIdx.y;
    const int base = blockIdx.x * W_WIN;
    const int tid  = threadIdx.x;
    const int lane = tid & 63;
    const int wid  = tid >> 6;

    if (tid == 0) cnt = 0;
    __syncthreads();
    for (int i = tid; i < W_WIN; i += BLK)
        if (lsi[base + i] == l) list[atomicAdd(&cnt, 1)] = (unsigned short)i;
    if (tid < 64)
        epiw[tid] = (tid < 32) ? l2_b[l * 32 + tid] : out_w[l * 32 + (tid - 32)];
    __syncthreads();
    const int n = cnt;
    if (n == 0) return;

    const int jlow  = lane & 15;
    const int g     = lane >> 4;
    const int col32 = lane & 31;
    const int h     = lane >> 5;

    // ---- persistent weights in registers (split-K: wave owns K-quarter) ----
    const float* wrow = l1_w + (((size_t)l * 16 + jlow) << 10);
    bf16x8 wfrag[8];
    #pragma unroll
    for (int i = 0; i < 8; ++i) {
        const int kf = (wid * 8 + i) * 32 + g * 8;
        wfrag[i] = cvt8(*(const float4*)(wrow + kf), *(const float4*)(wrow + kf + 4));
    }
    const float* w2row = l2_w + ((size_t)l * 32 + col32) * 16 + h * 8;
    const bf16x8 w2frag = cvt8(*(const float4*)(w2row), *(const float4*)(w2row + 4));
    const float l1bias = l1_b[l * 16 + jlow];
    const float outb   = out_b[l];

    const int srow  = tid >> 5;   // rows 8*rr + srow, rr=0..3
    const int scol8 = tid & 31;   // 8-float chunk lane
    const int pr    = tid >> 2;   // psq staging row (tid<128: 0..31)
    const int ppart = tid & 3;
    const int psf   = (ppart < 2) ? (512 + 4 * ppart) : (1032 + 4 * (ppart - 2));

    // ---- register prefetch (one 32-row tile in flight) ----
    float4 pfa[16], pfb[16], pfq;
    float usn = 0.f, usc; int pin = 0, pic;

    auto issue_pf = [&](int tbn) {
        #pragma unroll
        for (int rr = 0; rr < 4; ++rr) {
            const int mi = tbn + 8 * rr + srow;
            const int s  = base + list[mi < n ? mi : n - 1];
            const float* src = accum + (size_t)s * 1040;
            #pragma unroll
            for (int p = 0; p < 4; ++p) {
                const int sf = 8 * (scol8 + 32 * p) + (p >= 2 ? 8 : 0);
                pfa[rr * 4 + p] = *(const float4*)(src + sf);
                pfb[rr * 4 + p] = *(const float4*)(src + sf + 4);
            }
        }
        if (tid < 128) {
            const int mi = tbn + pr;
            const float* src = accum + (size_t)(base + list[mi < n ? mi : n - 1]) * 1040;
            pfq = *(const float4*)(src + psf);
        }
        if (lane < 16 && wid < 2) {
            const int mi = tbn + wid * 16 + jlow;
            const int s  = base + list[mi < n ? mi : n - 1];
            usn = us[s];
            pin = psqt_indices[s];
        }
    };

    auto stage = [&](int par) {
        #pragma unroll
        for (int rr = 0; rr < 4; ++rr) {
            const int row = 8 * rr + srow;
            #pragma unroll
            for (int p = 0; p < 4; ++p)
                *(bf16x8*)&At[atx(row, 8 * (scol8 + 32 * p))] =
                    cvt8(pfa[rr * 4 + p], pfb[rr * 4 + p]);
        }
        if (tid < 128) *(float4*)&psq[par][pr][ppart * 4] = pfq;
    };

    issue_pf(0);

    int par = 0;
    for (int tb = 0; tb < n; tb += 32, par ^= 1) {
        stage(par);
        __syncthreads();                       // At + psq[par] ready
        usc = usn; pic = pin;
        if (tb + 32 < n) issue_pf(tb + 32);    // stays in flight across compute+epi

        // ---- split-K MFMA: two 16-sample groups per wave ----
        f32x4 a0 = {0.f, 0.f, 0.f, 0.f};
        f32x4 a1 = {0.f, 0.f, 0.f, 0.f};
        #pragma unroll
        for (int i = 0; i < 8; ++i) {
            const int kf = (wid * 8 + i) * 32 + g * 8;
            bf16x8 f0 = *(const bf16x8*)&At[atx(jlow,      kf)];
            bf16x8 f1 = *(const bf16x8*)&At[atx(jlow + 16, kf)];
            a0 = __builtin_amdgcn_mfma_f32_16x16x32_bf16(f0, wfrag[i], a0, 0, 0, 0);
            a1 = __builtin_amdgcn_mfma_f32_16x16x32_bf16(f1, wfrag[i], a1, 0, 0, 0);
        }
        if (wid != 0) l1part[0][wid - 1][lane] = a0;              // g0: waves 1,2,3
        if (wid != 1) l1part[1][wid == 0 ? 0 : wid - 1][lane] = a1; // g1: waves 0,2,3
        __syncthreads();                       // l1part ready; At consumed

        // ---- dual parallel epilogue: wave0 -> group0, wave1 -> group1 ----
        if (wid < 2) {
            const int grp = wid;
            const f32x4 own = (wid == 0) ? a0 : a1;
            const f32x4 t0 = l1part[grp][0][lane];
            const f32x4 t1 = l1part[grp][1][lane];
            const f32x4 t2 = l1part[grp][2][lane];
            float* ly = l1y[grp];
            #pragma unroll
            for (int r = 0; r < 4; ++r) {
                float v = fminf(fmaxf(own[r] + t0[r] + t1[r] + t2[r] + l1bias, 0.f), 1.f);
                ly[(g * 4 + r) * 20 + jlow] = v;
            }
            __builtin_amdgcn_wave_barrier();
            asm volatile("s_waitcnt lgkmcnt(0)" ::: "memory");

            const float* lyr = ly + (col32 & 15) * 20 + h * 8;
            float4 y0 = *(const float4*)(lyr);
            float4 y1 = *(const float4*)(lyr + 4);
            const bf16x8 b2frag = cvt8(y0, y1);

            f32x16 acc2 = {};
            acc2 = __builtin_amdgcn_mfma_f32_32x32x16_bf16(w2frag, b2frag, acc2, 0, 0, 0);

            float partial = 0.f;
            #pragma unroll
            for (int r = 0; r < 16; ++r) {
                const int j2 = (r & 3) + 8 * (r >> 2) + 4 * h;
                float v = fminf(fmaxf(acc2[r] + epiw[j2], 0.f), 1.f);
                partial += v * epiw[32 + j2];
            }
            partial += __shfl_xor(partial, 32);

            const int mi = tb + grp * 16 + jlow;
            if (lane < 16 && mi < n) {
                const int s = base + list[mi];
                const float wp = psq[par][grp * 16 + jlow][pic];
                const float bp = psq[par][grp * 16 + jlow][8 + pic];
                out[s] = partial + outb + (wp - bp) * (usc - 0.5f);
            }
        }
        // no 3rd barrier: waves 2,3 proceed to stage(t+1); l1part/At WAR is
        // protected by the next iteration's first __syncthreads; psq is
        // parity-double-buffered.
    }
}

extern "C" void kernel_launch(void* const* d_in, const int* in_sizes, int n_in,
                              void* d_out, int out_size, void* d_ws, size_t ws_size,
                              hipStream_t stream) {
    const float* accum = (const float*)d_in[0];
    const float* us    = (const float*)d_in[1];
    const float* l1_w  = (const float*)d_in[2];
    const float* l1_b  = (const float*)d_in[3];
    const float* l2_w  = (const float*)d_in[4];
    const float* l2_b  = (const float*)d_in[5];
    const float* out_w = (const float*)d_in[6];
    const float* out_b = (const float*)d_in[7];
    const int*   psqt  = (const int*)d_in[8];
    const int*   lsi   = (const int*)d_in[9];
    float* out = (float*)d_out;

    dim3 grid(B_TOTAL / W_WIN, NCOUNT);
    nnue_mfma_kernel<<<grid, BLK, 0, stream>>>(
        accum, us, l1_w, l1_b, l2_w, l2_b, out_w, out_b, psqt, lsi, out);
}